// Round 12
// baseline (240.512 us; speedup 1.0000x reference)
//
#include <hip/hip_runtime.h>

#define C_DIM 256
#define CQK   32
#define N_DIM 4096
#define B_DIM 2

typedef __attribute__((ext_vector_type(8))) short bf16x8;
typedef __attribute__((ext_vector_type(4))) float f32x4;

__device__ __forceinline__ unsigned short f2bf(float f) {
    union { float f; unsigned u; } v; v.f = f;
    unsigned r = v.u + 0x7FFFu + ((v.u >> 16) & 1u);   // RNE
    return (unsigned short)(r >> 16);
}
// software RNE pack — used in qkv_proj staging/epilogue
__device__ __forceinline__ unsigned pk2(float a, float b) {
    return (unsigned)f2bf(a) | ((unsigned)f2bf(b) << 16);
}
// truncating pack via v_perm_b32 (1 VALU op): low16 = bf16_trunc(a), high = b
__device__ __forceinline__ unsigned pk2t(float a, float b) {
    union { float f; unsigned u; } ua, ub; ua.f = a; ub.f = b;
    return __builtin_amdgcn_perm(ub.u, ua.u, 0x07060302u);
}
#define EXP2(x) __builtin_amdgcn_exp2f(x)
#define MFMA(A, B, C) __builtin_amdgcn_mfma_f32_16x16x32_bf16((A), (B), (C), 0, 0, 0)

// ---------------------------------------------------------------------------
// Kernel 0: convert W (q|k|v rows, 320x256) to bf16 + gather biases.
// q rows (and q bias) pre-scaled by log2(e) so attn uses raw 2^x.
// ---------------------------------------------------------------------------
__global__ __launch_bounds__(256) void wconv(
    const float* __restrict__ q_w, const float* __restrict__ q_b,
    const float* __restrict__ k_w, const float* __restrict__ k_b,
    const float* __restrict__ v_w, const float* __restrict__ v_b,
    unsigned short* __restrict__ wbf, float* __restrict__ biasf)
{
    const float LOG2E = 1.4426950408889634f;
    int o = blockIdx.x, c = threadIdx.x;
    float w;
    if (o < 32)       w = q_w[o * C_DIM + c] * LOG2E;
    else if (o < 64)  w = k_w[(o - 32) * C_DIM + c];
    else              w = v_w[(o - 64) * C_DIM + c];
    wbf[o * C_DIM + c] = f2bf(w);
    if (c == 0) biasf[o] = (o < 32) ? q_b[o] * LOG2E
                         : (o < 64) ? k_b[o - 32] : v_b[o - 64];
}

// ---------------------------------------------------------------------------
// Kernel 1: QKV projection via MFMA, 16-col n-tiles. (R11-identical, proven)
// ---------------------------------------------------------------------------
__global__ __launch_bounds__(256, 2) void qkv_proj(
    const float* __restrict__ x, const unsigned short* __restrict__ wbf,
    const float* __restrict__ biasf,
    unsigned short* __restrict__ qT, unsigned short* __restrict__ kT,
    unsigned short* __restrict__ vbf)
{
    __shared__ __align__(16) unsigned short xsT[16 * 264];     // [n][c] bf16
    __shared__ __align__(16) unsigned short qkbuf[2][16 * 36]; // q/k bounce
    __shared__ __align__(16) unsigned short vbb[256 * 20];     // v bounce, stride 20
    const int t  = threadIdx.x;
    const int b  = blockIdx.x >> 8;
    const int n0 = (blockIdx.x & 255) * 16;

    {
        int n4 = t & 3, cq = t >> 2;   // cq 0..63
        const float* xp = x + ((size_t)(b * C_DIM + cq * 4)) * N_DIM + n0 + n4 * 4;
        float4 r0 = *(const float4*)xp;
        float4 r1 = *(const float4*)(xp + N_DIM);
        float4 r2 = *(const float4*)(xp + 2 * N_DIM);
        float4 r3 = *(const float4*)(xp + 3 * N_DIM);
        float a0[4], a1[4], a2[4], a3[4];
        *(float4*)a0 = r0; *(float4*)a1 = r1; *(float4*)a2 = r2; *(float4*)a3 = r3;
        #pragma unroll
        for (int k = 0; k < 4; ++k) {
            uint2 pw;
            pw.x = pk2(a0[k], a1[k]);
            pw.y = pk2(a2[k], a3[k]);
            *(uint2*)&xsT[(n4 * 4 + k) * 264 + cq * 4] = pw;
        }
    }
    __syncthreads();

    const int w = t >> 6, lid = t & 63, lr = lid & 15, lq = lid >> 4;
    f32x4 acc[5] = {};
    #pragma unroll
    for (int ks = 0; ks < 8; ++ks) {
        bf16x8 xb = *(const bf16x8*)&xsT[lr * 264 + ks * 32 + lq * 8];
        #pragma unroll
        for (int u = 0; u < 5; ++u) {
            int gm = w * 5 + u;
            bf16x8 af = *(const bf16x8*)&wbf[(gm * 16 + lr) * C_DIM + ks * 32 + lq * 8];
            acc[u] = MFMA(af, xb, acc[u]);
        }
    }
    #pragma unroll
    for (int u = 0; u < 5; ++u) {
        int gm = w * 5 + u;
        float bv[4];
        *(float4*)bv = *(const float4*)&biasf[gm * 16 + lq * 4];
        if (gm >= 4) {
            int vc = (gm - 4) * 16 + lq * 4;
            #pragma unroll
            for (int r = 0; r < 4; ++r)
                vbb[(vc + r) * 20 + lr] = f2bf(acc[u][r] + bv[r]);
        } else {
            int sel = gm >> 1, half = gm & 1;   // wave 0 only
            uint2 pw;
            pw.x = pk2(acc[u][0] + bv[0], acc[u][1] + bv[1]);
            pw.y = pk2(acc[u][2] + bv[2], acc[u][3] + bv[3]);
            *(uint2*)&qkbuf[sel][lr * 36 + half * 16 + lq * 4] = pw;
        }
    }
    __syncthreads();
    if (t < 128) {
        int sel = t >> 6, idx = t & 63;
        int n = idx >> 2, ch8 = (idx & 3) * 8;
        const unsigned short* src = &qkbuf[sel][n * 36 + ch8];
        uint2 a = *(const uint2*)src;
        uint2 c = *(const uint2*)(src + 4);
        unsigned short* dst = (sel ? kT : qT) + ((size_t)b * N_DIM + n0 + n) * CQK + ch8;
        uint4 st; st.x = a.x; st.y = a.y; st.z = c.x; st.w = c.y;
        *(uint4*)dst = st;
    }
    {
        const unsigned short* src = &vbb[t * 20];
        uint2 a = *(const uint2*)(src + 0);
        uint2 bq = *(const uint2*)(src + 4);
        uint2 c = *(const uint2*)(src + 8);
        uint2 d = *(const uint2*)(src + 12);
        unsigned short* dst = vbf + ((size_t)b * C_DIM + t) * N_DIM + n0;
        uint4 s0; s0.x = a.x; s0.y = a.y; s0.z = bq.x; s0.w = bq.y;
        uint4 s1; s1.x = c.x; s1.y = c.y; s1.z = d.x; s1.w = d.y;
        *(uint4*)dst = s0;
        *(uint4*)(dst + 8) = s1;
    }
}

// ---------------------------------------------------------------------------
// Kernel 2: MFMA flash attention — j-split across EIGHT waves, barrier-free
// K-loop. 512-thread blocks double waves/SIMD (2->4) at IDENTICAL L2 traffic:
// wave w owns j in [w*512, w*512+512), 16 iters of 32. Wave-private P in LDS.
// grid: b(2) x qt(64) x cs(4) = 512 blocks (2 blocks/CU = 16 waves/CU).
// __launch_bounds__(512,4) caps VGPR at 128 (R11 used 116 -> no spill).
// ---------------------------------------------------------------------------
__global__ __launch_bounds__(512, 4) void attn_kernel(
    const unsigned short* __restrict__ qT, const unsigned short* __restrict__ kT,
    const unsigned short* __restrict__ vbf, const float* __restrict__ x,
    const float* __restrict__ gamma, float* __restrict__ out)
{
    // P: 8 waves x [64 i][stride 40] bf16 = 40960B. obuf overlays P after
    // the loop ([64 c][68] f32 = 17408B). lbuf: [8][64] + [64] f32 = 2304B.
    __shared__ __align__(16) char smem[40960 + 2304];
    unsigned short* pbase = (unsigned short*)smem;
    float* obuf = (float*)smem;
    float* lbuf = (float*)(smem + 40960);

    const int t  = threadIdx.x;
    const int b  = blockIdx.x >> 8;
    const int qt = (blockIdx.x >> 2) & 63;
    const int cs = blockIdx.x & 3;
    const int i0 = qt * 64, c0 = cs * 64;
    const int w = t >> 6, lid = t & 63, lr = lid & 15, lq = lid >> 4;

    const unsigned short* qTb = qT + (size_t)b * N_DIM * CQK;
    const unsigned short* kTb = kT + (size_t)b * N_DIM * CQK;
    const unsigned short* vb  = vbf + (size_t)b * C_DIM * N_DIM;

    unsigned short* pW = pbase + w * (64 * 40);   // wave-private P region

    bf16x8 bq[4];
    #pragma unroll
    for (int it = 0; it < 4; ++it)
        bq[it] = *(const bf16x8*)&qTb[(i0 + it * 16 + lr) * CQK + lq * 8];

    f32x4 oa[4][4] = {};   // [ct][it]
    float lp[4] = {};

    const int jwbase = w * 512;
    // prologue: iter-0 K/V frags
    bf16x8 ak0 = *(const bf16x8*)&kTb[(jwbase + lr) * CQK + lq * 8];
    bf16x8 ak1 = *(const bf16x8*)&kTb[(jwbase + 16 + lr) * CQK + lq * 8];
    bf16x8 av[4];
    #pragma unroll
    for (int ct = 0; ct < 4; ++ct)
        av[ct] = *(const bf16x8*)&vb[(size_t)(c0 + ct * 16 + lr) * N_DIM + jwbase + lq * 8];

    #pragma unroll 2
    for (int jj = 0; jj < 512; jj += 32) {
        // prefetch next-iter K/V (latency covered by exp/pack below)
        const int jn = jwbase + ((jj + 32) & 511);
        bf16x8 ak0n = *(const bf16x8*)&kTb[(jn + lr) * CQK + lq * 8];
        bf16x8 ak1n = *(const bf16x8*)&kTb[(jn + 16 + lr) * CQK + lq * 8];
        bf16x8 avn[4];
        #pragma unroll
        for (int ct = 0; ct < 4; ++ct)
            avn[ct] = *(const bf16x8*)&vb[(size_t)(c0 + ct * 16 + lr) * N_DIM + jn + lq * 8];

        const f32x4 z = {};
        // S^T + 2^S + pack into wave-private P
        #pragma unroll
        for (int it = 0; it < 4; ++it) {
            f32x4 s0 = MFMA(ak0, bq[it], z);
            f32x4 s1 = MFMA(ak1, bq[it], z);
            float e0 = EXP2(s0[0]), e1 = EXP2(s0[1]), e2 = EXP2(s0[2]), e3 = EXP2(s0[3]);
            float f0 = EXP2(s1[0]), f1 = EXP2(s1[1]), f2 = EXP2(s1[2]), f3 = EXP2(s1[3]);
            lp[it] += ((e0 + e1) + (e2 + e3)) + ((f0 + f1) + (f2 + f3));
            uint2 pw0; pw0.x = pk2t(e0, e1); pw0.y = pk2t(e2, e3);
            uint2 pw1; pw1.x = pk2t(f0, f1); pw1.y = pk2t(f2, f3);
            unsigned short* prow = pW + (it * 16 + lr) * 40;
            *(uint2*)&prow[lq * 4]      = pw0;
            *(uint2*)&prow[16 + lq * 4] = pw1;
        }
        __asm__ __volatile__("" ::: "memory");   // keep ds_read after ds_write
        // PV
        #pragma unroll
        for (int it = 0; it < 4; ++it) {
            bf16x8 bp = *(const bf16x8*)&pW[(it * 16 + lr) * 40 + lq * 8];
            #pragma unroll
            for (int ct = 0; ct < 4; ++ct)
                oa[ct][it] = MFMA(av[ct], bp, oa[ct][it]);
        }
        // rotate prefetched frags
        ak0 = ak0n; ak1 = ak1n;
        #pragma unroll
        for (int ct = 0; ct < 4; ++ct) av[ct] = avn[ct];
    }

    // ---- l: reduce across lq within wave ----
    #pragma unroll
    for (int it = 0; it < 4; ++it) {
        lp[it] += __shfl_xor(lp[it], 16);
        lp[it] += __shfl_xor(lp[it], 32);
    }
    if (lq == 0) {
        #pragma unroll
        for (int it = 0; it < 4; ++it)
            lbuf[w * 64 + it * 16 + lr] = lp[it];
    }
    __syncthreads();   // all waves done loop; P regions dead -> obuf overlay ok

    // ---- sequential cross-wave O accumulate into obuf[c][i] ----
    for (int ph = 0; ph < 8; ++ph) {
        if (w == ph) {
            #pragma unroll
            for (int ct = 0; ct < 4; ++ct)
                #pragma unroll
                for (int it = 0; it < 4; ++it)
                    #pragma unroll
                    for (int r = 0; r < 4; ++r) {
                        int addr = (ct * 16 + lq * 4 + r) * 68 + it * 16 + lr;
                        if (ph == 0) obuf[addr]  = oa[ct][it][r];
                        else         obuf[addr] += oa[ct][it][r];
                    }
        }
        __syncthreads();
    }
    if (t < 64) {
        float l = 0.f;
        #pragma unroll
        for (int ww = 0; ww < 8; ++ww) l += lbuf[ww * 64 + t];
        lbuf[512 + t] = 1.f / l;
    }
    __syncthreads();

    // ---- epilogue: out = gamma*O/l + x, 8 elements/thread ----
    const float g = gamma[0];
    const int cc = t >> 3;            // 0..63 relative channel
    const int ic = (t & 7) * 8;       // i-chunk of 8
    const size_t rowbase = ((size_t)b * C_DIM + c0 + cc) * N_DIM + i0 + ic;
    #pragma unroll
    for (int k = 0; k < 2; ++k) {
        float4 ov4 = *(const float4*)&obuf[cc * 68 + ic + k * 4];
        float4 li  = *(const float4*)&lbuf[512 + ic + k * 4];
        float4 xv  = *(const float4*)(x + rowbase + k * 4);
        float4 ov;
        ov.x = g * ov4.x * li.x + xv.x;
        ov.y = g * ov4.y * li.y + xv.y;
        ov.z = g * ov4.z * li.z + xv.z;
        ov.w = g * ov4.w * li.w + xv.w;
        *(float4*)(out + rowbase + k * 4) = ov;
    }
}

extern "C" void kernel_launch(void* const* d_in, const int* in_sizes, int n_in,
                              void* d_out, int out_size, void* d_ws, size_t ws_size,
                              hipStream_t stream) {
    const float* x     = (const float*)d_in[0];
    const float* q_w   = (const float*)d_in[1];
    const float* q_b   = (const float*)d_in[2];
    const float* k_w   = (const float*)d_in[3];
    const float* k_b   = (const float*)d_in[4];
    const float* v_w   = (const float*)d_in[5];
    const float* v_b   = (const float*)d_in[6];
    const float* gamma = (const float*)d_in[7];
    float* out = (float*)d_out;

    char* ws = (char*)d_ws;
    unsigned short* qT    = (unsigned short*)(ws);             // 512KB
    unsigned short* kT    = (unsigned short*)(ws + 524288);    // 512KB
    unsigned short* vbf   = (unsigned short*)(ws + 1048576);   // 4MB
    unsigned short* wbf   = (unsigned short*)(ws + 5242880);   // 160KB
    float*          biasf = (float*)(ws + 5406720);            // 1.25KB

    hipLaunchKernelGGL(wconv, dim3(320), dim3(256), 0, stream,
                       q_w, q_b, k_w, k_b, v_w, v_b, wbf, biasf);
    hipLaunchKernelGGL(qkv_proj, dim3(B_DIM * 256), dim3(256), 0, stream,
                       x, wbf, biasf, qT, kT, vbf);
    hipLaunchKernelGGL(attn_kernel, dim3(B_DIM * 64 * 4), dim3(512), 0, stream,
                       qT, kT, vbf, x, gamma, out);
}

// Round 13
// 141.687 us; speedup vs baseline: 1.6975x; 1.6975x over previous
//
#include <hip/hip_runtime.h>

#define C_DIM 256
#define CQK   32
#define N_DIM 4096
#define B_DIM 2

typedef __attribute__((ext_vector_type(8))) short bf16x8;
typedef __attribute__((ext_vector_type(4))) float f32x4;

__device__ __forceinline__ unsigned short f2bf(float f) {
    union { float f; unsigned u; } v; v.f = f;
    unsigned r = v.u + 0x7FFFu + ((v.u >> 16) & 1u);   // RNE
    return (unsigned short)(r >> 16);
}
// software RNE pack — used in qkv_proj staging/epilogue
__device__ __forceinline__ unsigned pk2(float a, float b) {
    return (unsigned)f2bf(a) | ((unsigned)f2bf(b) << 16);
}
// truncating pack via v_perm_b32 (1 VALU op): low16 = bf16_trunc(a), high = b
__device__ __forceinline__ unsigned pk2t(float a, float b) {
    union { float f; unsigned u; } ua, ub; ua.f = a; ub.f = b;
    return __builtin_amdgcn_perm(ub.u, ua.u, 0x07060302u);
}
#define EXP2(x) __builtin_amdgcn_exp2f(x)
#define MFMA(A, B, C) __builtin_amdgcn_mfma_f32_16x16x32_bf16((A), (B), (C), 0, 0, 0)

// ---------------------------------------------------------------------------
// Kernel 0: convert W (q|k|v rows, 320x256) to bf16 + gather biases.
// q rows (and q bias) pre-scaled by log2(e) so attn uses raw 2^x.
// ---------------------------------------------------------------------------
__global__ __launch_bounds__(256) void wconv(
    const float* __restrict__ q_w, const float* __restrict__ q_b,
    const float* __restrict__ k_w, const float* __restrict__ k_b,
    const float* __restrict__ v_w, const float* __restrict__ v_b,
    unsigned short* __restrict__ wbf, float* __restrict__ biasf)
{
    const float LOG2E = 1.4426950408889634f;
    int o = blockIdx.x, c = threadIdx.x;
    float w;
    if (o < 32)       w = q_w[o * C_DIM + c] * LOG2E;
    else if (o < 64)  w = k_w[(o - 32) * C_DIM + c];
    else              w = v_w[(o - 64) * C_DIM + c];
    wbf[o * C_DIM + c] = f2bf(w);
    if (c == 0) biasf[o] = (o < 32) ? q_b[o] * LOG2E
                         : (o < 64) ? k_b[o - 32] : v_b[o - 64];
}

// ---------------------------------------------------------------------------
// Kernel 1: QKV projection via MFMA, 16-col n-tiles. (R11-identical, proven)
// ---------------------------------------------------------------------------
__global__ __launch_bounds__(256, 2) void qkv_proj(
    const float* __restrict__ x, const unsigned short* __restrict__ wbf,
    const float* __restrict__ biasf,
    unsigned short* __restrict__ qT, unsigned short* __restrict__ kT,
    unsigned short* __restrict__ vbf)
{
    __shared__ __align__(16) unsigned short xsT[16 * 264];     // [n][c] bf16
    __shared__ __align__(16) unsigned short qkbuf[2][16 * 36]; // q/k bounce
    __shared__ __align__(16) unsigned short vbb[256 * 20];     // v bounce, stride 20
    const int t  = threadIdx.x;
    const int b  = blockIdx.x >> 8;
    const int n0 = (blockIdx.x & 255) * 16;

    {
        int n4 = t & 3, cq = t >> 2;   // cq 0..63
        const float* xp = x + ((size_t)(b * C_DIM + cq * 4)) * N_DIM + n0 + n4 * 4;
        float4 r0 = *(const float4*)xp;
        float4 r1 = *(const float4*)(xp + N_DIM);
        float4 r2 = *(const float4*)(xp + 2 * N_DIM);
        float4 r3 = *(const float4*)(xp + 3 * N_DIM);
        float a0[4], a1[4], a2[4], a3[4];
        *(float4*)a0 = r0; *(float4*)a1 = r1; *(float4*)a2 = r2; *(float4*)a3 = r3;
        #pragma unroll
        for (int k = 0; k < 4; ++k) {
            uint2 pw;
            pw.x = pk2(a0[k], a1[k]);
            pw.y = pk2(a2[k], a3[k]);
            *(uint2*)&xsT[(n4 * 4 + k) * 264 + cq * 4] = pw;
        }
    }
    __syncthreads();

    const int w = t >> 6, lid = t & 63, lr = lid & 15, lq = lid >> 4;
    f32x4 acc[5] = {};
    #pragma unroll
    for (int ks = 0; ks < 8; ++ks) {
        bf16x8 xb = *(const bf16x8*)&xsT[lr * 264 + ks * 32 + lq * 8];
        #pragma unroll
        for (int u = 0; u < 5; ++u) {
            int gm = w * 5 + u;
            bf16x8 af = *(const bf16x8*)&wbf[(gm * 16 + lr) * C_DIM + ks * 32 + lq * 8];
            acc[u] = MFMA(af, xb, acc[u]);
        }
    }
    #pragma unroll
    for (int u = 0; u < 5; ++u) {
        int gm = w * 5 + u;
        float bv[4];
        *(float4*)bv = *(const float4*)&biasf[gm * 16 + lq * 4];
        if (gm >= 4) {
            int vc = (gm - 4) * 16 + lq * 4;
            #pragma unroll
            for (int r = 0; r < 4; ++r)
                vbb[(vc + r) * 20 + lr] = f2bf(acc[u][r] + bv[r]);
        } else {
            int sel = gm >> 1, half = gm & 1;   // wave 0 only
            uint2 pw;
            pw.x = pk2(acc[u][0] + bv[0], acc[u][1] + bv[1]);
            pw.y = pk2(acc[u][2] + bv[2], acc[u][3] + bv[3]);
            *(uint2*)&qkbuf[sel][lr * 36 + half * 16 + lq * 4] = pw;
        }
    }
    __syncthreads();
    if (t < 128) {
        int sel = t >> 6, idx = t & 63;
        int n = idx >> 2, ch8 = (idx & 3) * 8;
        const unsigned short* src = &qkbuf[sel][n * 36 + ch8];
        uint2 a = *(const uint2*)src;
        uint2 c = *(const uint2*)(src + 4);
        unsigned short* dst = (sel ? kT : qT) + ((size_t)b * N_DIM + n0 + n) * CQK + ch8;
        uint4 st; st.x = a.x; st.y = a.y; st.z = c.x; st.w = c.y;
        *(uint4*)dst = st;
    }
    {
        const unsigned short* src = &vbb[t * 20];
        uint2 a = *(const uint2*)(src + 0);
        uint2 bq = *(const uint2*)(src + 4);
        uint2 c = *(const uint2*)(src + 8);
        uint2 d = *(const uint2*)(src + 12);
        unsigned short* dst = vbf + ((size_t)b * C_DIM + t) * N_DIM + n0;
        uint4 s0; s0.x = a.x; s0.y = a.y; s0.z = bq.x; s0.w = bq.y;
        uint4 s1; s1.x = c.x; s1.y = c.y; s1.z = d.x; s1.w = d.y;
        *(uint4*)dst = s0;
        *(uint4*)(dst + 8) = s1;
    }
}

// ---------------------------------------------------------------------------
// Kernel 2: MFMA flash attention — j-split across EIGHT waves, barrier-free
// K-loop. 512-thread blocks, wave w owns j in [w*512, w*512+512), 16 iters.
// grid: b(2) x qt(64) x cs(4) = 512 blocks (2 blocks/CU = 16 waves/CU
// = 4 waves/SIMD). __launch_bounds__(512,2): 2 blocks/CU -> 128 VGPR cap
// (R12's (512,4) meant 4 blocks/CU -> 64 VGPRs -> 670MB spill traffic;
// measured VGPR_Count=64 confirmed blocks-per-CU semantics).
// ---------------------------------------------------------------------------
__global__ __launch_bounds__(512, 2) void attn_kernel(
    const unsigned short* __restrict__ qT, const unsigned short* __restrict__ kT,
    const unsigned short* __restrict__ vbf, const float* __restrict__ x,
    const float* __restrict__ gamma, float* __restrict__ out)
{
    // P: 8 waves x [64 i][stride 40] bf16 = 40960B. obuf overlays P after
    // the loop ([64 c][68] f32 = 17408B). lbuf: [8][64] + [64] f32 = 2304B.
    __shared__ __align__(16) char smem[40960 + 2304];
    unsigned short* pbase = (unsigned short*)smem;
    float* obuf = (float*)smem;
    float* lbuf = (float*)(smem + 40960);

    const int t  = threadIdx.x;
    const int b  = blockIdx.x >> 8;
    const int qt = (blockIdx.x >> 2) & 63;
    const int cs = blockIdx.x & 3;
    const int i0 = qt * 64, c0 = cs * 64;
    const int w = t >> 6, lid = t & 63, lr = lid & 15, lq = lid >> 4;

    const unsigned short* qTb = qT + (size_t)b * N_DIM * CQK;
    const unsigned short* kTb = kT + (size_t)b * N_DIM * CQK;
    const unsigned short* vb  = vbf + (size_t)b * C_DIM * N_DIM;

    unsigned short* pW = pbase + w * (64 * 40);   // wave-private P region

    bf16x8 bq[4];
    #pragma unroll
    for (int it = 0; it < 4; ++it)
        bq[it] = *(const bf16x8*)&qTb[(i0 + it * 16 + lr) * CQK + lq * 8];

    f32x4 oa[4][4] = {};   // [ct][it]
    float lp[4] = {};

    const int jwbase = w * 512;
    // prologue: iter-0 K/V frags
    bf16x8 ak0 = *(const bf16x8*)&kTb[(jwbase + lr) * CQK + lq * 8];
    bf16x8 ak1 = *(const bf16x8*)&kTb[(jwbase + 16 + lr) * CQK + lq * 8];
    bf16x8 av[4];
    #pragma unroll
    for (int ct = 0; ct < 4; ++ct)
        av[ct] = *(const bf16x8*)&vb[(size_t)(c0 + ct * 16 + lr) * N_DIM + jwbase + lq * 8];

    #pragma unroll 2
    for (int jj = 0; jj < 512; jj += 32) {
        // prefetch next-iter K/V (latency covered by exp/pack below)
        const int jn = jwbase + ((jj + 32) & 511);
        bf16x8 ak0n = *(const bf16x8*)&kTb[(jn + lr) * CQK + lq * 8];
        bf16x8 ak1n = *(const bf16x8*)&kTb[(jn + 16 + lr) * CQK + lq * 8];
        bf16x8 avn[4];
        #pragma unroll
        for (int ct = 0; ct < 4; ++ct)
            avn[ct] = *(const bf16x8*)&vb[(size_t)(c0 + ct * 16 + lr) * N_DIM + jn + lq * 8];

        const f32x4 z = {};
        // S^T + 2^S + pack into wave-private P
        #pragma unroll
        for (int it = 0; it < 4; ++it) {
            f32x4 s0 = MFMA(ak0, bq[it], z);
            f32x4 s1 = MFMA(ak1, bq[it], z);
            float e0 = EXP2(s0[0]), e1 = EXP2(s0[1]), e2 = EXP2(s0[2]), e3 = EXP2(s0[3]);
            float f0 = EXP2(s1[0]), f1 = EXP2(s1[1]), f2 = EXP2(s1[2]), f3 = EXP2(s1[3]);
            lp[it] += ((e0 + e1) + (e2 + e3)) + ((f0 + f1) + (f2 + f3));
            uint2 pw0; pw0.x = pk2t(e0, e1); pw0.y = pk2t(e2, e3);
            uint2 pw1; pw1.x = pk2t(f0, f1); pw1.y = pk2t(f2, f3);
            unsigned short* prow = pW + (it * 16 + lr) * 40;
            *(uint2*)&prow[lq * 4]      = pw0;
            *(uint2*)&prow[16 + lq * 4] = pw1;
        }
        __asm__ __volatile__("" ::: "memory");   // keep ds_read after ds_write
        // PV
        #pragma unroll
        for (int it = 0; it < 4; ++it) {
            bf16x8 bp = *(const bf16x8*)&pW[(it * 16 + lr) * 40 + lq * 8];
            #pragma unroll
            for (int ct = 0; ct < 4; ++ct)
                oa[ct][it] = MFMA(av[ct], bp, oa[ct][it]);
        }
        // rotate prefetched frags
        ak0 = ak0n; ak1 = ak1n;
        #pragma unroll
        for (int ct = 0; ct < 4; ++ct) av[ct] = avn[ct];
    }

    // ---- l: reduce across lq within wave ----
    #pragma unroll
    for (int it = 0; it < 4; ++it) {
        lp[it] += __shfl_xor(lp[it], 16);
        lp[it] += __shfl_xor(lp[it], 32);
    }
    if (lq == 0) {
        #pragma unroll
        for (int it = 0; it < 4; ++it)
            lbuf[w * 64 + it * 16 + lr] = lp[it];
    }
    __syncthreads();   // all waves done loop; P regions dead -> obuf overlay ok

    // ---- sequential cross-wave O accumulate into obuf[c][i] ----
    for (int ph = 0; ph < 8; ++ph) {
        if (w == ph) {
            #pragma unroll
            for (int ct = 0; ct < 4; ++ct)
                #pragma unroll
                for (int it = 0; it < 4; ++it)
                    #pragma unroll
                    for (int r = 0; r < 4; ++r) {
                        int addr = (ct * 16 + lq * 4 + r) * 68 + it * 16 + lr;
                        if (ph == 0) obuf[addr]  = oa[ct][it][r];
                        else         obuf[addr] += oa[ct][it][r];
                    }
        }
        __syncthreads();
    }
    if (t < 64) {
        float l = 0.f;
        #pragma unroll
        for (int ww = 0; ww < 8; ++ww) l += lbuf[ww * 64 + t];
        lbuf[512 + t] = 1.f / l;
    }
    __syncthreads();

    // ---- epilogue: out = gamma*O/l + x, 8 elements/thread ----
    const float g = gamma[0];
    const int cc = t >> 3;            // 0..63 relative channel
    const int ic = (t & 7) * 8;       // i-chunk of 8
    const size_t rowbase = ((size_t)b * C_DIM + c0 + cc) * N_DIM + i0 + ic;
    #pragma unroll
    for (int k = 0; k < 2; ++k) {
        float4 ov4 = *(const float4*)&obuf[cc * 68 + ic + k * 4];
        float4 li  = *(const float4*)&lbuf[512 + ic + k * 4];
        float4 xv  = *(const float4*)(x + rowbase + k * 4);
        float4 ov;
        ov.x = g * ov4.x * li.x + xv.x;
        ov.y = g * ov4.y * li.y + xv.y;
        ov.z = g * ov4.z * li.z + xv.z;
        ov.w = g * ov4.w * li.w + xv.w;
        *(float4*)(out + rowbase + k * 4) = ov;
    }
}

extern "C" void kernel_launch(void* const* d_in, const int* in_sizes, int n_in,
                              void* d_out, int out_size, void* d_ws, size_t ws_size,
                              hipStream_t stream) {
    const float* x     = (const float*)d_in[0];
    const float* q_w   = (const float*)d_in[1];
    const float* q_b   = (const float*)d_in[2];
    const float* k_w   = (const float*)d_in[3];
    const float* k_b   = (const float*)d_in[4];
    const float* v_w   = (const float*)d_in[5];
    const float* v_b   = (const float*)d_in[6];
    const float* gamma = (const float*)d_in[7];
    float* out = (float*)d_out;

    char* ws = (char*)d_ws;
    unsigned short* qT    = (unsigned short*)(ws);             // 512KB
    unsigned short* kT    = (unsigned short*)(ws + 524288);    // 512KB
    unsigned short* vbf   = (unsigned short*)(ws + 1048576);   // 4MB
    unsigned short* wbf   = (unsigned short*)(ws + 5242880);   // 160KB
    float*          biasf = (float*)(ws + 5406720);            // 1.25KB

    hipLaunchKernelGGL(wconv, dim3(320), dim3(256), 0, stream,
                       q_w, q_b, k_w, k_b, v_w, v_b, wbf, biasf);
    hipLaunchKernelGGL(qkv_proj, dim3(B_DIM * 256), dim3(256), 0, stream,
                       x, wbf, biasf, qT, kT, vbf);
    hipLaunchKernelGGL(attn_kernel, dim3(B_DIM * 64 * 4), dim3(512), 0, stream,
                       qT, kT, vbf, x, gamma, out);
}

// Round 14
// 132.096 us; speedup vs baseline: 1.8207x; 1.0726x over previous
//
#include <hip/hip_runtime.h>

#define C_DIM 256
#define CQK   32
#define N_DIM 4096
#define B_DIM 2

typedef __attribute__((ext_vector_type(8))) short bf16x8;
typedef __attribute__((ext_vector_type(4))) float f32x4;

__device__ __forceinline__ unsigned short f2bf(float f) {
    union { float f; unsigned u; } v; v.f = f;
    unsigned r = v.u + 0x7FFFu + ((v.u >> 16) & 1u);   // RNE
    return (unsigned short)(r >> 16);
}
__device__ __forceinline__ unsigned pk2(float a, float b) {
    return (unsigned)f2bf(a) | ((unsigned)f2bf(b) << 16);
}
// truncating pack via v_perm_b32 (1 VALU op): low16 = bf16_trunc(a), high = b
__device__ __forceinline__ unsigned pk2t(float a, float b) {
    union { float f; unsigned u; } ua, ub; ua.f = a; ub.f = b;
    return __builtin_amdgcn_perm(ub.u, ua.u, 0x07060302u);
}
#define EXP2(x) __builtin_amdgcn_exp2f(x)
#define MFMA(A, B, C) __builtin_amdgcn_mfma_f32_16x16x32_bf16((A), (B), (C), 0, 0, 0)

// ---------------------------------------------------------------------------
// Kernel 0: convert W (q|k|v rows, 320x256) to bf16 + gather biases.
// q rows (and q bias) pre-scaled by log2(e) so attn uses raw 2^x.
// ---------------------------------------------------------------------------
__global__ __launch_bounds__(256) void wconv(
    const float* __restrict__ q_w, const float* __restrict__ q_b,
    const float* __restrict__ k_w, const float* __restrict__ k_b,
    const float* __restrict__ v_w, const float* __restrict__ v_b,
    unsigned short* __restrict__ wbf, float* __restrict__ biasf)
{
    const float LOG2E = 1.4426950408889634f;
    int o = blockIdx.x, c = threadIdx.x;
    float w;
    if (o < 32)       w = q_w[o * C_DIM + c] * LOG2E;
    else if (o < 64)  w = k_w[(o - 32) * C_DIM + c];
    else              w = v_w[(o - 64) * C_DIM + c];
    wbf[o * C_DIM + c] = f2bf(w);
    if (c == 0) biasf[o] = (o < 32) ? q_b[o] * LOG2E
                         : (o < 64) ? k_b[o - 32] : v_b[o - 64];
}

// ---------------------------------------------------------------------------
// Kernel 1: QKV projection via MFMA, 16-col n-tiles. (R11-identical, proven)
// ---------------------------------------------------------------------------
__global__ __launch_bounds__(256, 2) void qkv_proj(
    const float* __restrict__ x, const unsigned short* __restrict__ wbf,
    const float* __restrict__ biasf,
    unsigned short* __restrict__ qT, unsigned short* __restrict__ kT,
    unsigned short* __restrict__ vbf)
{
    __shared__ __align__(16) unsigned short xsT[16 * 264];     // [n][c] bf16
    __shared__ __align__(16) unsigned short qkbuf[2][16 * 36]; // q/k bounce
    __shared__ __align__(16) unsigned short vbb[256 * 20];     // v bounce, stride 20
    const int t  = threadIdx.x;
    const int b  = blockIdx.x >> 8;
    const int n0 = (blockIdx.x & 255) * 16;

    {
        int n4 = t & 3, cq = t >> 2;   // cq 0..63
        const float* xp = x + ((size_t)(b * C_DIM + cq * 4)) * N_DIM + n0 + n4 * 4;
        float4 r0 = *(const float4*)xp;
        float4 r1 = *(const float4*)(xp + N_DIM);
        float4 r2 = *(const float4*)(xp + 2 * N_DIM);
        float4 r3 = *(const float4*)(xp + 3 * N_DIM);
        float a0[4], a1[4], a2[4], a3[4];
        *(float4*)a0 = r0; *(float4*)a1 = r1; *(float4*)a2 = r2; *(float4*)a3 = r3;
        #pragma unroll
        for (int k = 0; k < 4; ++k) {
            uint2 pw;
            pw.x = pk2(a0[k], a1[k]);
            pw.y = pk2(a2[k], a3[k]);
            *(uint2*)&xsT[(n4 * 4 + k) * 264 + cq * 4] = pw;
        }
    }
    __syncthreads();

    const int w = t >> 6, lid = t & 63, lr = lid & 15, lq = lid >> 4;
    f32x4 acc[5] = {};
    #pragma unroll
    for (int ks = 0; ks < 8; ++ks) {
        bf16x8 xb = *(const bf16x8*)&xsT[lr * 264 + ks * 32 + lq * 8];
        #pragma unroll
        for (int u = 0; u < 5; ++u) {
            int gm = w * 5 + u;
            bf16x8 af = *(const bf16x8*)&wbf[(gm * 16 + lr) * C_DIM + ks * 32 + lq * 8];
            acc[u] = MFMA(af, xb, acc[u]);
        }
    }
    #pragma unroll
    for (int u = 0; u < 5; ++u) {
        int gm = w * 5 + u;
        float bv[4];
        *(float4*)bv = *(const float4*)&biasf[gm * 16 + lq * 4];
        if (gm >= 4) {
            int vc = (gm - 4) * 16 + lq * 4;
            #pragma unroll
            for (int r = 0; r < 4; ++r)
                vbb[(vc + r) * 20 + lr] = f2bf(acc[u][r] + bv[r]);
        } else {
            int sel = gm >> 1, half = gm & 1;   // wave 0 only
            uint2 pw;
            pw.x = pk2(acc[u][0] + bv[0], acc[u][1] + bv[1]);
            pw.y = pk2(acc[u][2] + bv[2], acc[u][3] + bv[3]);
            *(uint2*)&qkbuf[sel][lr * 36 + half * 16 + lq * 4] = pw;
        }
    }
    __syncthreads();
    if (t < 128) {
        int sel = t >> 6, idx = t & 63;
        int n = idx >> 2, ch8 = (idx & 3) * 8;
        const unsigned short* src = &qkbuf[sel][n * 36 + ch8];
        uint2 a = *(const uint2*)src;
        uint2 c = *(const uint2*)(src + 4);
        unsigned short* dst = (sel ? kT : qT) + ((size_t)b * N_DIM + n0 + n) * CQK + ch8;
        uint4 st; st.x = a.x; st.y = a.y; st.z = c.x; st.w = c.y;
        *(uint4*)dst = st;
    }
    {
        const unsigned short* src = &vbb[t * 20];
        uint2 a = *(const uint2*)(src + 0);
        uint2 bq = *(const uint2*)(src + 4);
        uint2 c = *(const uint2*)(src + 8);
        uint2 d = *(const uint2*)(src + 12);
        unsigned short* dst = vbf + ((size_t)b * C_DIM + t) * N_DIM + n0;
        uint4 s0; s0.x = a.x; s0.y = a.y; s0.z = bq.x; s0.w = bq.y;
        uint4 s1; s1.x = c.x; s1.y = c.y; s1.z = d.x; s1.w = d.y;
        *(uint4*)dst = s0;
        *(uint4*)(dst + 8) = s1;
    }
}

// ---------------------------------------------------------------------------
// Kernel 2: MFMA flash attention — j-split across 4 waves, barrier-free,
// SOFTWARE-PIPELINED: double-buffered wave-private P. Iter k: read P(k-1)
// from buf[(k-1)&1] for PV while exp/pack writes P(k) to buf[k&1] — no
// write->read lgkmcnt stall; PV MFMAs (matrix pipe) overlap exp (trans pipe).
// grid: b(2) x qt(64) x cs(4) = 512 blocks, 256 threads (4 waves x 1024 j).
// ---------------------------------------------------------------------------
__global__ __launch_bounds__(256, 2) void attn_kernel(
    const unsigned short* __restrict__ qT, const unsigned short* __restrict__ kT,
    const unsigned short* __restrict__ vbf, const float* __restrict__ x,
    const float* __restrict__ gamma, float* __restrict__ out)
{
    // P: 4 waves x 2 bufs x [64 i][stride 40] bf16 = 40960B.
    // obuf overlays P after the loop ([64 c][68] f32 = 17408B).
    // lbuf: [4][64] partial l + [64] linv = 1280B.
    __shared__ __align__(16) char smem[40960 + 1536];
    unsigned short* pbase = (unsigned short*)smem;
    float* obuf = (float*)smem;
    float* lbuf = (float*)(smem + 40960);

    const int t  = threadIdx.x;
    const int b  = blockIdx.x >> 8;
    const int qt = (blockIdx.x >> 2) & 63;
    const int cs = blockIdx.x & 3;
    const int i0 = qt * 64, c0 = cs * 64;
    const int w = t >> 6, lid = t & 63, lr = lid & 15, lq = lid >> 4;

    const unsigned short* qTb = qT + (size_t)b * N_DIM * CQK;
    const unsigned short* kTb = kT + (size_t)b * N_DIM * CQK;
    const unsigned short* vb  = vbf + (size_t)b * C_DIM * N_DIM;

    unsigned short* pW0 = pbase + (w * 2 + 0) * (64 * 40);
    unsigned short* pW1 = pbase + (w * 2 + 1) * (64 * 40);

    bf16x8 bq[4];
    #pragma unroll
    for (int it = 0; it < 4; ++it)
        bq[it] = *(const bf16x8*)&qTb[(i0 + it * 16 + lr) * CQK + lq * 8];

    f32x4 oa[4][4] = {};   // [ct][it]
    float lp[4] = {};

    const int jwbase = w * 1024;   // 32 iters of 32 j

    // prologue: K(0)
    bf16x8 akc0 = *(const bf16x8*)&kTb[(jwbase + lr) * CQK + lq * 8];
    bf16x8 akc1 = *(const bf16x8*)&kTb[(jwbase + 16 + lr) * CQK + lq * 8];
    bf16x8 avU[4];   // V(k-1), consumed by PV at iter k

    // ---- peeled iter 0: S(0)+exp -> P(0) in pW0; issue V(0), K(1) ----
    {
        #pragma unroll
        for (int ct = 0; ct < 4; ++ct)
            avU[ct] = *(const bf16x8*)&vb[(size_t)(c0 + ct * 16 + lr) * N_DIM + jwbase + lq * 8];
        bf16x8 akn0 = *(const bf16x8*)&kTb[(jwbase + 32 + lr) * CQK + lq * 8];
        bf16x8 akn1 = *(const bf16x8*)&kTb[(jwbase + 32 + 16 + lr) * CQK + lq * 8];
        const f32x4 z = {};
        #pragma unroll
        for (int it = 0; it < 4; ++it) {
            f32x4 s0 = MFMA(akc0, bq[it], z);
            f32x4 s1 = MFMA(akc1, bq[it], z);
            float e0 = EXP2(s0[0]), e1 = EXP2(s0[1]), e2 = EXP2(s0[2]), e3 = EXP2(s0[3]);
            float f0 = EXP2(s1[0]), f1 = EXP2(s1[1]), f2 = EXP2(s1[2]), f3 = EXP2(s1[3]);
            lp[it] += ((e0 + e1) + (e2 + e3)) + ((f0 + f1) + (f2 + f3));
            uint2 pw0; pw0.x = pk2t(e0, e1); pw0.y = pk2t(e2, e3);
            uint2 pw1; pw1.x = pk2t(f0, f1); pw1.y = pk2t(f2, f3);
            unsigned short* prow = pW0 + (it * 16 + lr) * 40;
            *(uint2*)&prow[lq * 4]      = pw0;
            *(uint2*)&prow[16 + lq * 4] = pw1;
        }
        akc0 = akn0; akc1 = akn1;
    }

    // ---- steady state k = 1..31 ----
    #pragma unroll 2
    for (int k = 1; k < 32; ++k) {
        const int j0 = jwbase + k * 32;
        const int jn = jwbase + ((k + 1) & 31) * 32;
        // V(k) in flight (consumed by PV at iter k+1 / drain)
        bf16x8 avI[4];
        #pragma unroll
        for (int ct = 0; ct < 4; ++ct)
            avI[ct] = *(const bf16x8*)&vb[(size_t)(c0 + ct * 16 + lr) * N_DIM + j0 + lq * 8];
        // K(k+1) in flight
        bf16x8 akn0 = *(const bf16x8*)&kTb[(jn + lr) * CQK + lq * 8];
        bf16x8 akn1 = *(const bf16x8*)&kTb[(jn + 16 + lr) * CQK + lq * 8];
        // P(k-1) reads from buf[(k-1)&1] — no dependency on this iter's work
        const unsigned short* pR = (k & 1) ? pW0 : pW1;
        bf16x8 bp[4];
        #pragma unroll
        for (int it = 0; it < 4; ++it)
            bp[it] = *(const bf16x8*)&pR[(it * 16 + lr) * 40 + lq * 8];
        // S(k)
        const f32x4 z = {};
        f32x4 s[4][2];
        #pragma unroll
        for (int it = 0; it < 4; ++it) {
            s[it][0] = MFMA(akc0, bq[it], z);
            s[it][1] = MFMA(akc1, bq[it], z);
        }
        // PV(k-1): overlaps the exp/pack below via matrix-vs-trans pipes
        #pragma unroll
        for (int it = 0; it < 4; ++it)
            #pragma unroll
            for (int ct = 0; ct < 4; ++ct)
                oa[ct][it] = MFMA(avU[ct], bp[it], oa[ct][it]);
        // exp + pack + write P(k) to buf[k&1]
        unsigned short* pWc = (k & 1) ? pW1 : pW0;
        #pragma unroll
        for (int it = 0; it < 4; ++it) {
            float e0 = EXP2(s[it][0][0]), e1 = EXP2(s[it][0][1]);
            float e2 = EXP2(s[it][0][2]), e3 = EXP2(s[it][0][3]);
            float f0 = EXP2(s[it][1][0]), f1 = EXP2(s[it][1][1]);
            float f2 = EXP2(s[it][1][2]), f3 = EXP2(s[it][1][3]);
            lp[it] += ((e0 + e1) + (e2 + e3)) + ((f0 + f1) + (f2 + f3));
            uint2 pw0; pw0.x = pk2t(e0, e1); pw0.y = pk2t(e2, e3);
            uint2 pw1; pw1.x = pk2t(f0, f1); pw1.y = pk2t(f2, f3);
            unsigned short* prow = pWc + (it * 16 + lr) * 40;
            *(uint2*)&prow[lq * 4]      = pw0;
            *(uint2*)&prow[16 + lq * 4] = pw1;
        }
        // rotate
        akc0 = akn0; akc1 = akn1;
        #pragma unroll
        for (int ct = 0; ct < 4; ++ct) avU[ct] = avI[ct];
    }

    // ---- drain: PV(31), P(31) in pW1 ----
    {
        bf16x8 bp[4];
        #pragma unroll
        for (int it = 0; it < 4; ++it)
            bp[it] = *(const bf16x8*)&pW1[(it * 16 + lr) * 40 + lq * 8];
        #pragma unroll
        for (int it = 0; it < 4; ++it)
            #pragma unroll
            for (int ct = 0; ct < 4; ++ct)
                oa[ct][it] = MFMA(avU[ct], bp[it], oa[ct][it]);
    }

    // ---- l: reduce across lq within wave ----
    #pragma unroll
    for (int it = 0; it < 4; ++it) {
        lp[it] += __shfl_xor(lp[it], 16);
        lp[it] += __shfl_xor(lp[it], 32);
    }
    if (lq == 0) {
        #pragma unroll
        for (int it = 0; it < 4; ++it)
            lbuf[w * 64 + it * 16 + lr] = lp[it];
    }
    __syncthreads();   // all waves done; P regions dead -> obuf overlay ok

    // ---- sequential cross-wave O accumulate into obuf[c][i] ----
    for (int ph = 0; ph < 4; ++ph) {
        if (w == ph) {
            #pragma unroll
            for (int ct = 0; ct < 4; ++ct)
                #pragma unroll
                for (int it = 0; it < 4; ++it)
                    #pragma unroll
                    for (int r = 0; r < 4; ++r) {
                        int addr = (ct * 16 + lq * 4 + r) * 68 + it * 16 + lr;
                        if (ph == 0) obuf[addr]  = oa[ct][it][r];
                        else         obuf[addr] += oa[ct][it][r];
                    }
        }
        __syncthreads();
    }
    if (t < 64) {
        float l = lbuf[t] + lbuf[64 + t] + lbuf[128 + t] + lbuf[192 + t];
        lbuf[256 + t] = 1.f / l;
    }
    __syncthreads();

    // ---- epilogue: out = gamma*O/l + x ----
    const float g = gamma[0];
    const int cc = t >> 2;
    const int ic = (t & 3) * 16;
    const size_t rowbase = ((size_t)b * C_DIM + c0 + cc) * N_DIM + i0 + ic;
    #pragma unroll
    for (int k = 0; k < 4; ++k) {
        float4 ov4 = *(const float4*)&obuf[cc * 68 + ic + k * 4];
        float4 li  = *(const float4*)&lbuf[256 + ic + k * 4];
        float4 xv  = *(const float4*)(x + rowbase + k * 4);
        float4 ov;
        ov.x = g * ov4.x * li.x + xv.x;
        ov.y = g * ov4.y * li.y + xv.y;
        ov.z = g * ov4.z * li.z + xv.z;
        ov.w = g * ov4.w * li.w + xv.w;
        *(float4*)(out + rowbase + k * 4) = ov;
    }
}

extern "C" void kernel_launch(void* const* d_in, const int* in_sizes, int n_in,
                              void* d_out, int out_size, void* d_ws, size_t ws_size,
                              hipStream_t stream) {
    const float* x     = (const float*)d_in[0];
    const float* q_w   = (const float*)d_in[1];
    const float* q_b   = (const float*)d_in[2];
    const float* k_w   = (const float*)d_in[3];
    const float* k_b   = (const float*)d_in[4];
    const float* v_w   = (const float*)d_in[5];
    const float* v_b   = (const float*)d_in[6];
    const float* gamma = (const float*)d_in[7];
    float* out = (float*)d_out;

    char* ws = (char*)d_ws;
    unsigned short* qT    = (unsigned short*)(ws);             // 512KB
    unsigned short* kT    = (unsigned short*)(ws + 524288);    // 512KB
    unsigned short* vbf   = (unsigned short*)(ws + 1048576);   // 4MB
    unsigned short* wbf   = (unsigned short*)(ws + 5242880);   // 160KB
    float*          biasf = (float*)(ws + 5406720);            // 1.25KB

    hipLaunchKernelGGL(wconv, dim3(320), dim3(256), 0, stream,
                       q_w, q_b, k_w, k_b, v_w, v_b, wbf, biasf);
    hipLaunchKernelGGL(qkv_proj, dim3(B_DIM * 256), dim3(256), 0, stream,
                       x, wbf, biasf, qT, kT, vbf);
    hipLaunchKernelGGL(attn_kernel, dim3(B_DIM * 64 * 4), dim3(256), 0, stream,
                       qT, kT, vbf, x, gamma, out);
}